// Round 1
// baseline (1315.462 us; speedup 1.0000x reference)
//
#include <hip/hip_runtime.h>
#include <cstdint>

#define KT 9408      // K_TOTAL
#define NT 512       // o-tile per block
#define KC 8         // k sub-chunk staged in LDS
#define KSPLIT 16    // K-split factor (partial sums)

// ---------------------------------------------------------------------------
// Partial GEMM:  partial[s][b][o] = sum_{k in split s} X[b,k] * W[o,k]
// Dual-source: concatenated K = K1 (X1,W1) then K2 (X2,W2). M = 32 fixed.
// Block: 256 threads, o-tile NT=512, thread register tile = 8 b x 8 o.
// ---------------------------------------------------------------------------
__global__ __launch_bounds__(256) void gemm32_partial(
    const float* __restrict__ X1, const float* __restrict__ W1, int K1,
    const float* __restrict__ X2, const float* __restrict__ W2, int K2,
    float* __restrict__ partial, int O)
{
    __shared__ float Xs[KC][32];        // [k_local][b]
    __shared__ float Ws[NT][KC + 1];    // [o_local][k_local], pad -> conflict-free reads

    const int t      = threadIdx.x;
    const int o0     = blockIdx.x * NT;
    const int s      = blockIdx.y;
    const int Ktot   = K1 + K2;
    const int kchunk = (Ktot + KSPLIT - 1) / KSPLIT;
    const int kbeg   = s * kchunk;
    const int kend   = min(kbeg + kchunk, Ktot);
    const int lane_o = t & 63;          // same 0..63 range in every wave
    const int tb     = t >> 6;          // wave id -> b-group (8 b's)

    float acc[8][8];
#pragma unroll
    for (int bi = 0; bi < 8; bi++)
#pragma unroll
        for (int j = 0; j < 8; j++) acc[bi][j] = 0.f;

    for (int kc0 = kbeg; kc0 < kend; kc0 += KC) {
        // ---- stage X chunk (transposed): Xs[c][b], 256 elements, 1/thread
        {
            int c  = t >> 5;
            int bb = t & 31;
            int kg = kc0 + c;
            float v = 0.f;
            if (kg < kend)
                v = (kg < K1) ? X1[(size_t)bb * K1 + kg]
                              : X2[(size_t)bb * K2 + (kg - K1)];
            Xs[c][bb] = v;
        }
        // ---- stage W tile: NT*KC = 4096 floats, 16/thread (4 x float4 spans)
#pragma unroll
        for (int it = 0; it < 4; ++it) {
            int lin = t + 256 * it;       // 0..1023
            int r   = lin >> 1;           // 0..511
            int c4  = (lin & 1) << 2;     // 0 or 4
            int o   = o0 + r;
            if (o < O) {
                int kg = kc0 + c4;
#pragma unroll
                for (int jj = 0; jj < 4; jj++) {
                    int k = kg + jj;
                    float v = 0.f;
                    if (k < kend)
                        v = (k < K1) ? W1[(size_t)o * K1 + k]
                                     : W2[(size_t)o * K2 + (k - K1)];
                    Ws[r][c4 + jj] = v;
                }
            }
        }
        __syncthreads();

        // ---- compute: 8 k-steps x (8b x 8o) FMAs
#pragma unroll
        for (int c = 0; c < KC; c++) {
            float4 xa = *(const float4*)&Xs[c][tb * 8];
            float4 xb = *(const float4*)&Xs[c][tb * 8 + 4];
            float xv[8] = {xa.x, xa.y, xa.z, xa.w, xb.x, xb.y, xb.z, xb.w};
            float w[8];
#pragma unroll
            for (int j = 0; j < 8; j++) w[j] = Ws[lane_o + 64 * j][c];
#pragma unroll
            for (int bi = 0; bi < 8; bi++)
#pragma unroll
                for (int j = 0; j < 8; j++) acc[bi][j] += xv[bi] * w[j];
        }
        __syncthreads();
    }

    // ---- store partials (coalesced over o)
#pragma unroll
    for (int bi = 0; bi < 8; bi++) {
        int b = tb * 8 + bi;
#pragma unroll
        for (int j = 0; j < 8; j++) {
            int o = o0 + lane_o + 64 * j;
            if (o < O)
                partial[((size_t)s * 32 + b) * O + o] = acc[bi][j];
        }
    }
}

// ---------------------------------------------------------------------------
// Reduce K-split partials + bias(es) + optional ReLU.  Y is [32][O] row-major.
// ---------------------------------------------------------------------------
__global__ __launch_bounds__(256) void reduce_bias(
    const float* __restrict__ partial, const float* __restrict__ bias1,
    const float* __restrict__ bias2, float* __restrict__ Y, int O, int relu)
{
    int idx = blockIdx.x * 256 + threadIdx.x;
    if (idx >= 32 * O) return;
    int b = idx / O, o = idx - b * O;
    float s = bias1[o] + (bias2 ? bias2[o] : 0.f);
#pragma unroll
    for (int k = 0; k < KSPLIT; k++)
        s += partial[((size_t)k * 32 + b) * O + o];
    Y[idx] = relu ? fmaxf(s, 0.f) : s;
}

// ---------------------------------------------------------------------------
// Fused per-pixel conv chain. One thread = one pixel; weights are
// block-uniform (sample b) -> scalar loads. Fully unrolled, register arrays.
// ks layout per sample: k_in[64*32] | k_mid[64*64] | k_out[32*64] |
//                       k_short[32*32] | b_in[64] | b_mid[64] | b_out[32] | b_short[32]
// ---------------------------------------------------------------------------
__global__ __launch_bounds__(256) void conv_fused(
    const float* __restrict__ x, const float* __restrict__ ks,
    float* __restrict__ out)
{
    const int b = blockIdx.y;
    const int p = blockIdx.x * 256 + threadIdx.x;   // 0..16383
    const float* __restrict__ kb = ks + (size_t)b * KT;
    const float* __restrict__ xb = x + (size_t)b * 32 * 16384 + p;

    float xv[32];
#pragma unroll
    for (int i = 0; i < 32; i++) xv[i] = xb[(size_t)i * 16384];

    // shortcut: k_short @ x + b_short
    float o_[32];
#pragma unroll
    for (int oo = 0; oo < 32; oo++) {
        float a = kb[9376 + oo];
#pragma unroll
        for (int i = 0; i < 32; i++) a += kb[8192 + oo * 32 + i] * xv[i];
        o_[oo] = a;
    }
    // layer in: relu(k_in @ x + b_in)
    float h[64];
#pragma unroll
    for (int oo = 0; oo < 64; oo++) {
        float a = kb[9216 + oo];
#pragma unroll
        for (int i = 0; i < 32; i++) a += kb[oo * 32 + i] * xv[i];
        h[oo] = fmaxf(a, 0.f);
    }
    // layer mid: relu(k_mid @ h + b_mid)
    float m[64];
#pragma unroll
    for (int oo = 0; oo < 64; oo++) {
        float a = kb[9280 + oo];
#pragma unroll
        for (int j = 0; j < 64; j++) a += kb[2048 + oo * 64 + j] * h[j];
        m[oo] = fmaxf(a, 0.f);
    }
    // layer out: k_out @ m + b_out, plus shortcut
#pragma unroll
    for (int oo = 0; oo < 32; oo++) {
        float a = kb[9344 + oo];
#pragma unroll
        for (int j = 0; j < 64; j++) a += kb[6144 + oo * 64 + j] * m[j];
        out[((size_t)b * 32 + oo) * 16384 + p] = o_[oo] + a;
    }
}

// ---------------------------------------------------------------------------
extern "C" void kernel_launch(void* const* d_in, const int* in_sizes, int n_in,
                              void* d_out, int out_size, void* d_ws, size_t ws_size,
                              hipStream_t stream)
{
    const float* x   = (const float*)d_in[0];
    const float* lat = (const float*)d_in[1];
    const float* w0  = (const float*)d_in[2];
    const float* b0  = (const float*)d_in[3];
    const float* w1a = (const float*)d_in[4];
    const float* b1a = (const float*)d_in[5];
    const float* w1b = (const float*)d_in[6];
    const float* b1b = (const float*)d_in[7];
    const float* w1s = (const float*)d_in[8];
    const float* b1s = (const float*)d_in[9];
    const float* w2a = (const float*)d_in[10];
    const float* b2a = (const float*)d_in[11];
    const float* w2b = (const float*)d_in[12];
    const float* b2b = (const float*)d_in[13];
    const float* w2s = (const float*)d_in[14];
    const float* b2s = (const float*)d_in[15];
    const float* wfa = (const float*)d_in[16];
    const float* bfa = (const float*)d_in[17];

    // intermediates in d_ws (needs ~2.8 MB)
    float* ws  = (float*)d_ws;
    float* h0  = ws;               // 32*512
    float* t1  = ws + 16384;       // 32*1024
    float* h1  = ws + 49152;       // 32*512
    float* t2  = ws + 65536;       // 32*1024
    float* h2  = ws + 98304;       // 32*9408
    float* ksb = ws + 399360;      // 32*9408
    // K-split partials live in d_out (19.3 MB < 64 MB); conv overwrites at end.
    float* pbuf = (float*)d_out;

    dim3 blk(256);
    auto g  = [](int O) { return dim3((unsigned)((O + NT - 1) / NT), KSPLIT); };
    auto rg = [](int O) { return dim3((unsigned)((32 * O + 255) / 256)); };

    // h0 = lat @ w0.T + b0
    gemm32_partial<<<g(512), blk, 0, stream>>>(lat, w0, 512, nullptr, nullptr, 0, pbuf, 512);
    reduce_bias<<<rg(512), blk, 0, stream>>>(pbuf, b0, nullptr, h0, 512, 0);
    // t1 = relu(h0 @ w1a.T + b1a)
    gemm32_partial<<<g(1024), blk, 0, stream>>>(h0, w1a, 512, nullptr, nullptr, 0, pbuf, 1024);
    reduce_bias<<<rg(1024), blk, 0, stream>>>(pbuf, b1a, nullptr, t1, 1024, 1);
    // h1 = h0 @ w1s.T + b1s + t1 @ w1b.T + b1b
    gemm32_partial<<<g(512), blk, 0, stream>>>(h0, w1s, 512, t1, w1b, 1024, pbuf, 512);
    reduce_bias<<<rg(512), blk, 0, stream>>>(pbuf, b1s, b1b, h1, 512, 0);
    // t2 = relu(h1 @ w2a.T + b2a)
    gemm32_partial<<<g(1024), blk, 0, stream>>>(h1, w2a, 512, nullptr, nullptr, 0, pbuf, 1024);
    reduce_bias<<<rg(1024), blk, 0, stream>>>(pbuf, b2a, nullptr, t2, 1024, 1);
    // h2 = h1 @ w2s.T + b2s + t2 @ w2b.T + b2b
    gemm32_partial<<<g(KT), blk, 0, stream>>>(h1, w2s, 512, t2, w2b, 1024, pbuf, KT);
    reduce_bias<<<rg(KT), blk, 0, stream>>>(pbuf, b2s, b2b, h2, KT, 0);
    // ks = h2 @ wfa.T + bfa
    gemm32_partial<<<g(KT), blk, 0, stream>>>(h2, wfa, KT, nullptr, nullptr, 0, pbuf, KT);
    reduce_bias<<<rg(KT), blk, 0, stream>>>(pbuf, bfa, nullptr, ksb, KT, 0);

    // fused per-sample 1x1 conv chain
    conv_fused<<<dim3(64, 32), blk, 0, stream>>>(x, ksb, (float*)d_out);
}

// Round 2
// 1063.944 us; speedup vs baseline: 1.2364x; 1.2364x over previous
//
#include <hip/hip_runtime.h>
#include <cstdint>

#define KT 9408      // K_TOTAL
#define NT 512       // o-tile per block
#define KC 16        // k sub-chunk staged in LDS

// ---------------------------------------------------------------------------
// Partial GEMM:  partial[s][b][o] = sum_{k in split s} X[b,k] * W[o,k]
// Dual-source: concatenated K = K1 (X1,W1) then K2 (X2,W2). M = 32 fixed.
// Block: 256 threads, o-tile NT=512, thread register tile = 8 b x 8 o.
// Caller guarantees: Ktot % ksplit == 0 and (Ktot/ksplit) % 16 == 0 or %4==0.
// ---------------------------------------------------------------------------
__global__ __launch_bounds__(256, 3) void gemm32_partial(
    const float* __restrict__ X1, const float* __restrict__ W1, int K1,
    const float* __restrict__ X2, const float* __restrict__ W2, int K2,
    float* __restrict__ partial, int O, int ksplit)
{
    __shared__ float Xs[KC][32];     // [k_local][b]
    __shared__ float Wt[KC][NT];     // [k_local][o_local] transposed -> conflict-free

    const int t      = threadIdx.x;
    const int o0     = blockIdx.x * NT;
    const int s      = blockIdx.y;
    const int Ktot   = K1 + K2;
    const int kchunk = Ktot / ksplit;          // %4 == 0 by construction
    const int kbeg   = s * kchunk;
    const int kend   = kbeg + kchunk;
    const int lane_o = t & 63;
    const int tb     = t >> 6;                 // wave id -> b-group (8 b's)

    float acc[8][8];
#pragma unroll
    for (int bi = 0; bi < 8; bi++)
#pragma unroll
        for (int j = 0; j < 8; j++) acc[bi][j] = 0.f;

    for (int kc0 = kbeg; kc0 < kend; kc0 += KC) {
        // ---- stage X chunk (transposed): Xs[c][b], KC*32=512 elems, 2/thread
#pragma unroll
        for (int it = 0; it < 2; ++it) {
            int idx = t + 256 * it;            // 0..511
            int c   = idx >> 5;
            int bb  = idx & 31;
            int kg  = kc0 + c;
            float v = 0.f;
            if (kg < kend)
                v = (kg < K1) ? X1[(size_t)bb * K1 + kg]
                              : X2[(size_t)bb * K2 + (kg - K1)];
            Xs[c][bb] = v;
        }
        // ---- stage W tile transposed: NT*KC floats as 2048 float4, 8/thread.
        // it: c4=(it&3)*4, r=(it>>2)*256+t  -> each thread reads 64B-contiguous
        // spans of 2 rows; LDS writes are lane-consecutive (conflict-free).
#pragma unroll
        for (int it = 0; it < 8; ++it) {
            int c4 = (it & 3) << 2;
            int r  = ((it >> 2) << 8) + t;
            int o  = o0 + r;
            int kg = kc0 + c4;
            float4 v = make_float4(0.f, 0.f, 0.f, 0.f);
            if (o < O && kg < kend)
                v = (kg < K1) ? *(const float4*)&W1[(size_t)o * K1 + kg]
                              : *(const float4*)&W2[(size_t)o * K2 + (kg - K1)];
            Wt[c4 + 0][r] = v.x;
            Wt[c4 + 1][r] = v.y;
            Wt[c4 + 2][r] = v.z;
            Wt[c4 + 3][r] = v.w;
        }
        __syncthreads();

        // ---- compute: KC k-steps x (8b x 8o) FMAs
#pragma unroll
        for (int c = 0; c < KC; c++) {
            float4 xa = *(const float4*)&Xs[c][tb * 8];       // wave-broadcast
            float4 xb = *(const float4*)&Xs[c][tb * 8 + 4];
            float xv[8] = {xa.x, xa.y, xa.z, xa.w, xb.x, xb.y, xb.z, xb.w};
            float w[8];
#pragma unroll
            for (int j = 0; j < 8; j++) w[j] = Wt[c][lane_o + 64 * j];
#pragma unroll
            for (int bi = 0; bi < 8; bi++)
#pragma unroll
                for (int j = 0; j < 8; j++) acc[bi][j] += xv[bi] * w[j];
        }
        __syncthreads();
    }

    // ---- store partials (coalesced over o)
#pragma unroll
    for (int bi = 0; bi < 8; bi++) {
        int b = tb * 8 + bi;
#pragma unroll
        for (int j = 0; j < 8; j++) {
            int o = o0 + lane_o + 64 * j;
            if (o < O)
                partial[((size_t)s * 32 + b) * O + o] = acc[bi][j];
        }
    }
}

// ---------------------------------------------------------------------------
// Reduce K-split partials + bias(es) + optional ReLU.  Y is [32][O] row-major.
// ---------------------------------------------------------------------------
__global__ __launch_bounds__(256) void reduce_bias(
    const float* __restrict__ partial, const float* __restrict__ bias1,
    const float* __restrict__ bias2, float* __restrict__ Y, int O, int relu,
    int ksplit)
{
    int idx = blockIdx.x * 256 + threadIdx.x;
    if (idx >= 32 * O) return;
    int b = idx / O, o = idx - b * O;
    float s = bias1[o] + (bias2 ? bias2[o] : 0.f);
    for (int k = 0; k < ksplit; k++)
        s += partial[((size_t)k * 32 + b) * O + o];
    Y[idx] = relu ? fmaxf(s, 0.f) : s;
}

// ---------------------------------------------------------------------------
// Fused per-pixel conv chain. One thread = one pixel; weights are
// block-uniform (sample b) -> scalar loads. Mid layer computed in chunks of 8
// fused into out accumulators so peak live set ~145 VGPRs (no spills).
// ks layout per sample: k_in[64*32] | k_mid[64*64] | k_out[32*64] |
//                       k_short[32*32] | b_in[64] | b_mid[64] | b_out[32] | b_short[32]
// ---------------------------------------------------------------------------
__global__ __launch_bounds__(256, 3) void conv_fused(
    const float* __restrict__ x, const float* __restrict__ ks,
    float* __restrict__ out)
{
    const int b = blockIdx.y;
    const int p = blockIdx.x * 256 + threadIdx.x;   // 0..16383
    const float* __restrict__ kb = ks + (size_t)b * KT;
    const float* __restrict__ xb = x + (size_t)b * 32 * 16384 + p;

    float xv[32];
#pragma unroll
    for (int i = 0; i < 32; i++) xv[i] = xb[(size_t)i * 16384];

    // shortcut + out-bias: o_ = k_short @ x + b_short + b_out
    float o_[32];
#pragma unroll
    for (int oo = 0; oo < 32; oo++) {
        float a = kb[9376 + oo] + kb[9344 + oo];
#pragma unroll
        for (int i = 0; i < 32; i++) a += kb[8192 + oo * 32 + i] * xv[i];
        o_[oo] = a;
    }
    // layer in: h = relu(k_in @ x + b_in)
    float h[64];
#pragma unroll
    for (int oo = 0; oo < 64; oo++) {
        float a = kb[9216 + oo];
#pragma unroll
        for (int i = 0; i < 32; i++) a += kb[oo * 32 + i] * xv[i];
        h[oo] = fmaxf(a, 0.f);
    }
    // xv dead from here. mid layer in chunks of 8, fused into o_ accumulation.
#pragma unroll
    for (int c = 0; c < 64; c += 8) {
        float m[8];
#pragma unroll
        for (int j = 0; j < 8; j++) {
            float a = kb[9280 + c + j];
#pragma unroll
            for (int q = 0; q < 64; q++) a += kb[2048 + (c + j) * 64 + q] * h[q];
            m[j] = fmaxf(a, 0.f);
        }
#pragma unroll
        for (int oo = 0; oo < 32; oo++) {
            float a = o_[oo];
#pragma unroll
            for (int j = 0; j < 8; j++) a += kb[6144 + oo * 64 + c + j] * m[j];
            o_[oo] = a;
        }
    }
#pragma unroll
    for (int oo = 0; oo < 32; oo++)
        out[((size_t)b * 32 + oo) * 16384 + p] = o_[oo];
}

// ---------------------------------------------------------------------------
extern "C" void kernel_launch(void* const* d_in, const int* in_sizes, int n_in,
                              void* d_out, int out_size, void* d_ws, size_t ws_size,
                              hipStream_t stream)
{
    const float* x   = (const float*)d_in[0];
    const float* lat = (const float*)d_in[1];
    const float* w0  = (const float*)d_in[2];
    const float* b0  = (const float*)d_in[3];
    const float* w1a = (const float*)d_in[4];
    const float* b1a = (const float*)d_in[5];
    const float* w1b = (const float*)d_in[6];
    const float* b1b = (const float*)d_in[7];
    const float* w1s = (const float*)d_in[8];
    const float* b1s = (const float*)d_in[9];
    const float* w2a = (const float*)d_in[10];
    const float* b2a = (const float*)d_in[11];
    const float* w2b = (const float*)d_in[12];
    const float* b2b = (const float*)d_in[13];
    const float* w2s = (const float*)d_in[14];
    const float* b2s = (const float*)d_in[15];
    const float* wfa = (const float*)d_in[16];
    const float* bfa = (const float*)d_in[17];

    // intermediates in d_ws (~2.8 MB)
    float* ws  = (float*)d_ws;
    float* h0  = ws;               // 32*512
    float* t1  = ws + 16384;       // 32*1024
    float* h1  = ws + 49152;       // 32*512
    float* t2  = ws + 65536;       // 32*1024
    float* h2  = ws + 98304;       // 32*9408
    float* ksb = ws + 399360;      // 32*9408
    // K-split partials live in d_out (<=33.7 MB < 64 MB); conv overwrites at end.
    float* pbuf = (float*)d_out;

    dim3 blk(256);
    auto g  = [](int O, int ks) { return dim3((unsigned)((O + NT - 1) / NT), (unsigned)ks); };
    auto rg = [](int O) { return dim3((unsigned)((32 * O + 255) / 256)); };

    // h0 = lat @ w0.T + b0                      (K=512, split 16 -> chunk 32)
    gemm32_partial<<<g(512, 16), blk, 0, stream>>>(lat, w0, 512, nullptr, nullptr, 0, pbuf, 512, 16);
    reduce_bias<<<rg(512), blk, 0, stream>>>(pbuf, b0, nullptr, h0, 512, 0, 16);
    // t1 = relu(h0 @ w1a.T + b1a)               (K=512)
    gemm32_partial<<<g(1024, 16), blk, 0, stream>>>(h0, w1a, 512, nullptr, nullptr, 0, pbuf, 1024, 16);
    reduce_bias<<<rg(1024), blk, 0, stream>>>(pbuf, b1a, nullptr, t1, 1024, 1, 16);
    // h1 = h0 @ w1s.T + b1s + t1 @ w1b.T + b1b  (K=1536 -> chunk 96)
    gemm32_partial<<<g(512, 16), blk, 0, stream>>>(h0, w1s, 512, t1, w1b, 1024, pbuf, 512, 16);
    reduce_bias<<<rg(512), blk, 0, stream>>>(pbuf, b1s, b1b, h1, 512, 0, 16);
    // t2 = relu(h1 @ w2a.T + b2a)               (K=512)
    gemm32_partial<<<g(1024, 16), blk, 0, stream>>>(h1, w2a, 512, nullptr, nullptr, 0, pbuf, 1024, 16);
    reduce_bias<<<rg(1024), blk, 0, stream>>>(pbuf, b2a, nullptr, t2, 1024, 1, 16);
    // h2 = h1 @ w2s.T + b2s + t2 @ w2b.T + b2b  (K=1536 -> chunk 96)
    gemm32_partial<<<g(KT, 16), blk, 0, stream>>>(h1, w2s, 512, t2, w2b, 1024, pbuf, KT, 16);
    reduce_bias<<<rg(KT), blk, 0, stream>>>(pbuf, b2s, b2b, h2, KT, 0, 16);
    // ks = h2 @ wfa.T + bfa                     (K=9408, split 28 -> chunk 336, 532 blocks)
    gemm32_partial<<<g(KT, 28), blk, 0, stream>>>(h2, wfa, KT, nullptr, nullptr, 0, pbuf, KT, 28);
    reduce_bias<<<rg(KT), blk, 0, stream>>>(pbuf, bfa, nullptr, ksb, KT, 0, 28);

    // fused per-sample 1x1 conv chain
    conv_fused<<<dim3(64, 32), blk, 0, stream>>>(x, ksb, (float*)d_out);
}